// Round 3
// baseline (379.272 us; speedup 1.0000x reference)
//
#include <hip/hip_runtime.h>
#include <hip/hip_bf16.h>

// B=2, S=2048, D=1024, H=16, HD=64.  All matmuls in bf16 MFMA (16x16x32).
// d_out = [ LN output (2*2048*1024 f32) | attention (2*16*2048*2048 f32) ]

typedef float f32x4 __attribute__((ext_vector_type(4)));
typedef short short8 __attribute__((ext_vector_type(8)));

#if __has_builtin(__builtin_amdgcn_exp2f)
#define EXP2(x) __builtin_amdgcn_exp2f(x)
#else
#define EXP2(x) exp2f(x)
#endif

#define QSCALE 0.18033688011112042f   /* log2(e)/8 : folds 1/sqrt(64) and exp->exp2 */
#define MASKNEG -1.4426950408889634e9f /* -1e9 * log2(e) -> exp2() == 0 */

// mid-iter barrier: staging (issued before the 16 P stores) must be done; the
// 16 newest vmem ops (the stores) may stay in flight across the barrier (T4).
#define BAR_DRAIN16() asm volatile("s_waitcnt vmcnt(16) lgkmcnt(0)\ns_barrier" ::: "memory")
// end-of-iter barrier: no vmem drain; lgkm guards LDS reads vs next DMA overwrite.
#define BAR_LGKM()    asm volatile("s_waitcnt lgkmcnt(0)\ns_barrier" ::: "memory")

__device__ __forceinline__ short f2bs(float f) {
  union { __hip_bfloat16 h; short s; } u;
  u.h = __float2bfloat16(f);
  return u.s;
}

__device__ __forceinline__ void async16(const void* g, void* l) {
  __builtin_amdgcn_global_load_lds(
      (const __attribute__((address_space(1))) unsigned int*)g,
      (__attribute__((address_space(3))) unsigned int*)l, 16, 0, 0);
}

// ---------------- K0: fp32 -> bf16 convert + mask bitmask (fused) ----------------
__global__ __launch_bounds__(256) void cvt_mask_kernel(
    const float* __restrict__ q, const float* __restrict__ k, const float* __restrict__ v,
    const float* __restrict__ wq, const float* __restrict__ wk, const float* __restrict__ wv,
    const float* __restrict__ wo, short* __restrict__ dst,
    const int* __restrict__ mask, unsigned* __restrict__ bits, unsigned* __restrict__ flags) {
  if (blockIdx.x < 8192) {
    long base = (long)blockIdx.x * 2048;  // block-uniform source select
    const float* src;
    if      (base <  4194304) src = q  + base;
    else if (base <  8388608) src = k  + (base - 4194304);
    else if (base < 12582912) src = v  + (base - 8388608);
    else if (base < 13631488) src = wq + (base - 12582912);
    else if (base < 14680064) src = wk + (base - 13631488);
    else if (base < 15728640) src = wv + (base - 14680064);
    else                      src = wo + (base - 15728640);
    int off = threadIdx.x * 8;
    float4 a = *(const float4*)(src + off);
    float4 b = *(const float4*)(src + off + 4);
    short8 o;
    o[0] = f2bs(a.x); o[1] = f2bs(a.y); o[2] = f2bs(a.z); o[3] = f2bs(a.w);
    o[4] = f2bs(b.x); o[5] = f2bs(b.y); o[6] = f2bs(b.z); o[7] = f2bs(b.w);
    *(short8*)(dst + base + off) = o;
  } else {
    int bid = blockIdx.x - 8192;
    int t = threadIdx.x, w = t >> 6, lane = t & 63;
    for (int it = 0; it < 16; ++it) {
      long gw = (long)it * 8192 + bid * 4 + w;
      long base = gw * 64;
      int mv = mask[base + lane];
      unsigned long long m = __ballot(mv != 0);
      if (lane == 0)  bits[gw * 2]     = (unsigned)m;
      if (lane == 32) bits[gw * 2 + 1] = (unsigned)(m >> 32);
      if (lane == 0 && m != 0xFFFFFFFFFFFFFFFFull) {
        long j = base & 2047, i = (base >> 11) & 2047, b = base >> 22;
        atomicOr(&flags[(int)(b * 256 + (i >> 7) * 16 + (j >> 7))], 1u);
      }
    }
  }
}

// ---------------- K1: QKV projection GEMM (128x128x64 tiles) ----------------
// mode 0: Qh[b][h][s][d] = (q@Wq^T + bq) * QSCALE
// mode 1: Kh[b][h][s][d] = (k@Wk^T + bk)
// mode 2: Vt[b][h][d][s] = (v@Wv^T + bv)   (plain transpose)
__global__ __launch_bounds__(256, 2) void proj_kernel(
    const short* __restrict__ Abase, const short* __restrict__ Wbase,
    const float* __restrict__ bq, const float* __restrict__ bk, const float* __restrict__ bv,
    short* __restrict__ Qh, short* __restrict__ Kh, short* __restrict__ Vt) {
  __shared__ __align__(16) short As[128 * 64];
  __shared__ __align__(16) short Bs[128 * 64];
  const int mode = blockIdx.z;
  const short* A = Abase + (size_t)mode * 4194304;
  const short* W = Wbase + (size_t)mode * 1048576;
  const float* bias = (mode == 0) ? bq : (mode == 1 ? bk : bv);
  const int t = threadIdx.x, w = t >> 6, lane = t & 63, g = lane >> 4, lc = lane & 15;
  const int wrow = (w >> 1) * 64, wcol = (w & 1) * 64;
  const int m0 = blockIdx.x * 128, n0 = blockIdx.y * 128;
  f32x4 acc[4][4] = {};
  for (int kt = 0; kt < 16; ++kt) {
    const int k0 = kt * 64;
    __syncthreads();
#pragma unroll
    for (int i = 0; i < 4; i++) {
      int cb = i * 256 + w * 64, ch = cb + lane, row = ch >> 3, c = ch & 7;
      async16(A + (size_t)(m0 + row) * 1024 + k0 + ((c ^ (row & 7)) << 3), (void*)&As[cb << 3]);
    }
#pragma unroll
    for (int i = 0; i < 4; i++) {
      int cb = i * 256 + w * 64, ch = cb + lane, row = ch >> 3, c = ch & 7;
      async16(W + (size_t)(n0 + row) * 1024 + k0 + ((c ^ (row & 7)) << 3), (void*)&Bs[cb << 3]);
    }
    __syncthreads();
#pragma unroll
    for (int kf = 0; kf < 2; ++kf) {
      short8 af[4], bf[4];
#pragma unroll
      for (int m = 0; m < 4; m++) {
        int row = wrow + m * 16 + lc;
        af[m] = *(const short8*)&As[(row << 6) + (((kf * 4 + g) ^ (row & 7)) << 3)];
      }
#pragma unroll
      for (int n = 0; n < 4; n++) {
        int row = wcol + n * 16 + lc;
        bf[n] = *(const short8*)&Bs[(row << 6) + (((kf * 4 + g) ^ (row & 7)) << 3)];
      }
#pragma unroll
      for (int m = 0; m < 4; m++)
#pragma unroll
        for (int n = 0; n < 4; n++)
          acc[m][n] = __builtin_amdgcn_mfma_f32_16x16x32_bf16(af[m], bf[n], acc[m][n], 0, 0, 0);
    }
  }
#pragma unroll
  for (int n = 0; n < 4; n++) {
    const int col = n0 + wcol + n * 16 + lc;
    const float bv_ = bias[col];
    const int h = col >> 6, d = col & 63;
#pragma unroll
    for (int m = 0; m < 4; m++)
#pragma unroll
      for (int r = 0; r < 4; r++) {
        const int srow = m0 + wrow + m * 16 + g * 4 + r;
        const int b = srow >> 11, s = srow & 2047;
        float val = acc[m][n][r] + bv_;
        if (mode == 0)
          Qh[((size_t)(b * 16 + h) * 2048 + s) * 64 + d] = f2bs(val * QSCALE);
        else if (mode == 1)
          Kh[((size_t)(b * 16 + h) * 2048 + s) * 64 + d] = f2bs(val);
        else
          Vt[((size_t)(b * 16 + h) * 64 + d) * 2048 + s] = f2bs(val);
      }
  }
}

// ---------------- K2: fused attention ----------------
// Pass A (swapped QK^T): row sums l only (no max; scores are O(1), exp2-safe).
// Pass B: recompute S with j permuted so each lane owns 8 consecutive j ->
//         dwordx4 nt P stores, b128 Ps writes, plain V^T chunks.
// Counted-vmcnt barriers keep P stores in flight across barriers (T4).
__global__ __launch_bounds__(256, 2) void attn_kernel(
    const short* __restrict__ Qh, const short* __restrict__ Kh, const short* __restrict__ Vt,
    const unsigned* __restrict__ mbits, const unsigned* __restrict__ mflags,
    float* __restrict__ Pout, short* __restrict__ ctx) {
  __shared__ __align__(16) short Ks[2][128 * 64];  // double-buffered K tile
  __shared__ __align__(16) short Vs[64 * 128];     // V^T tile [d][j], chunk c = j in [8c,8c+8)
  __shared__ __align__(16) short Ps[128 * 128];    // P tile  [i][j], chunk c = j in [8c,8c+8)
  // XCD swizzle: xcd gets 4 bh, 16 qb each -> K/V working set 2MB per XCD L2
  const int L = blockIdx.x;
  const int xcd = L & 7, idx = L >> 3;
  const int bh = xcd + ((idx >> 4) << 3);
  const int qb = idx & 15;
  const int b = bh >> 4, h = bh & 15;
  const int t = threadIdx.x, w = t >> 6, lane = t & 63, g = lane >> 4, lc = lane & 15;
  const short* Qp = Qh + (size_t)bh * 2048 * 64;
  const short* Kp = Kh + (size_t)bh * 2048 * 64;
  const short* Vp = Vt + (size_t)bh * 64 * 2048;
  float* Pb = Pout + ((size_t)bh * 2048 + qb * 128) * 2048;

  short8 qf[2][2];
#pragma unroll
  for (int qm = 0; qm < 2; qm++)
#pragma unroll
    for (int kf = 0; kf < 2; kf++)
      qf[qm][kf] = *(const short8*)(Qp + (size_t)(qb * 128 + w * 32 + qm * 16 + lc) * 64 + kf * 32 + g * 8);

#define STAGE_K(buf, j0)                                                                   \
  do {                                                                                     \
    _Pragma("unroll") for (int i_ = 0; i_ < 4; i_++) {                                     \
      int cb = i_ * 256 + w * 64, ch = cb + lane, row = ch >> 3, c = ch & 7;               \
      int sc = c ^ (row & 7) ^ ((row >> 3) & 7);                                           \
      async16(Kp + (size_t)((j0) + row) * 64 + (sc << 3), (void*)&Ks[buf][cb << 3]);       \
    }                                                                                      \
  } while (0)
#define STAGE_V(j0)                                                                        \
  do {                                                                                     \
    _Pragma("unroll") for (int i_ = 0; i_ < 4; i_++) {                                     \
      int cb = i_ * 256 + w * 64, ch = cb + lane, row = ch >> 4, c = ch & 15;              \
      async16(Vp + (size_t)row * 2048 + (j0) + ((c ^ (row & 15)) << 3), (void*)&Vs[cb << 3]); \
    }                                                                                      \
  } while (0)

  // ---- pass A: l only, swapped operands ----
  float lsum[2] = {0.f, 0.f};
  int kb = 0;
  STAGE_K(0, 0);
  __syncthreads();
  for (int it = 0; it < 16; ++it) {
    if (it < 15) STAGE_K(kb ^ 1, (it + 1) * 128);
    f32x4 acc[2][8] = {};
    __builtin_amdgcn_s_setprio(1);
#pragma unroll
    for (int kf = 0; kf < 2; kf++)
#pragma unroll
      for (int n = 0; n < 8; n++) {
        int row = n * 16 + lc;
        int sc = (kf * 4 + g) ^ (row & 7) ^ ((row >> 3) & 7);
        short8 kfr = *(const short8*)&Ks[kb][(row << 6) + (sc << 3)];
        acc[0][n] = __builtin_amdgcn_mfma_f32_16x16x32_bf16(kfr, qf[0][kf], acc[0][n], 0, 0, 0);
        acc[1][n] = __builtin_amdgcn_mfma_f32_16x16x32_bf16(kfr, qf[1][kf], acc[1][n], 0, 0, 0);
      }
    __builtin_amdgcn_s_setprio(0);
    unsigned flg = mflags[b * 256 + qb * 16 + it];
    if (flg) {
#pragma unroll
      for (int qm = 0; qm < 2; qm++) {
        int ig = qb * 128 + w * 32 + qm * 16 + lc;
        uint4 mw = *(const uint4*)(mbits + ((size_t)b * 2048 + ig) * 64 + it * 4);
#pragma unroll
        for (int n = 0; n < 8; n++) {
          unsigned bw = (n >> 1) == 0 ? mw.x : ((n >> 1) == 1 ? mw.y : ((n >> 1) == 2 ? mw.z : mw.w));
#pragma unroll
          for (int r = 0; r < 4; r++)
            if (!((bw >> (((n & 1) << 4) + g * 4 + r)) & 1u)) acc[qm][n][r] = MASKNEG;
        }
      }
    }
#pragma unroll
    for (int qm = 0; qm < 2; qm++) {
      float s_ = 0.f;
#pragma unroll
      for (int n = 0; n < 8; n++)
#pragma unroll
        for (int r = 0; r < 4; r++) s_ += EXP2(acc[qm][n][r]);
      s_ += __shfl_xor(s_, 16);
      s_ += __shfl_xor(s_, 32);
      lsum[qm] += s_;
    }
    __syncthreads();  // drains prefetch (no stores in flight in pass A)
    kb ^= 1;
  }
  // exchange l across lanes via LDS (Vs unused so far)
  float* ls = (float*)Vs;
  if (g == 0) { ls[w * 32 + lc] = lsum[0]; ls[w * 32 + 16 + lc] = lsum[1]; }
  __syncthreads();
  float linv[8];
#pragma unroll
  for (int qm = 0; qm < 2; qm++)
#pragma unroll
    for (int r = 0; r < 4; r++) linv[qm * 4 + r] = 1.0f / ls[w * 32 + qm * 16 + g * 4 + r];
  kb = 0;
  STAGE_K(0, 0);
  __syncthreads();  // all lanes read ls before Vs overwritten; Ks[0] ready

  // ---- pass B ----
  f32x4 acco[2][4] = {};
  for (int it = 0; it < 16; ++it) {
    const int j0 = it * 128;
    STAGE_V(j0);
    if (it < 15) STAGE_K(kb ^ 1, j0 + 128);
    f32x4 accs[2][8] = {};
    __builtin_amdgcn_s_setprio(1);
#pragma unroll
    for (int kf = 0; kf < 2; kf++)
#pragma unroll
      for (int n = 0; n < 8; n++) {
        int row = lc * 8 + n;  // permuted j: lane lc owns j in [8lc, 8lc+8)
        int sc = (kf * 4 + g) ^ n ^ (lc & 7);
        short8 kfr = *(const short8*)&Ks[kb][(row << 6) + (sc << 3)];
        accs[0][n] = __builtin_amdgcn_mfma_f32_16x16x32_bf16(qf[0][kf], kfr, accs[0][n], 0, 0, 0);
        accs[1][n] = __builtin_amdgcn_mfma_f32_16x16x32_bf16(qf[1][kf], kfr, accs[1][n], 0, 0, 0);
      }
    __builtin_amdgcn_s_setprio(0);
    unsigned flg = mflags[b * 256 + qb * 16 + it];
    if (flg) {
#pragma unroll
      for (int qm = 0; qm < 2; qm++)
#pragma unroll
        for (int r = 0; r < 4; r++) {
          int ig = qb * 128 + w * 32 + qm * 16 + g * 4 + r;
          uint4 mw = *(const uint4*)(mbits + ((size_t)b * 2048 + ig) * 64 + it * 4);
          unsigned w01 = (lc & 4) ? mw.y : mw.x;
          unsigned w23 = (lc & 4) ? mw.w : mw.z;
          unsigned wsel = (lc & 8) ? w23 : w01;
#pragma unroll
          for (int n = 0; n < 8; n++)
            if (!((wsel >> (((lc & 3) << 3) + n)) & 1u)) accs[qm][n][r] = MASKNEG;
        }
    }
    // P = exp2(s) / l : two nt dwordx4 global stores + one b128 LDS write per (qm,r)
#pragma unroll
    for (int qm = 0; qm < 2; qm++)
#pragma unroll
      for (int r = 0; r < 4; r++) {
        const float li = linv[qm * 4 + r];
        const int irow = w * 32 + qm * 16 + g * 4 + r;
        f32x4 p0, p1;
#pragma unroll
        for (int n = 0; n < 4; n++) p0[n] = EXP2(accs[qm][n][r]) * li;
#pragma unroll
        for (int n = 0; n < 4; n++) p1[n] = EXP2(accs[qm][n + 4][r]) * li;
        f32x4* pr = (f32x4*)(Pb + (size_t)irow * 2048 + j0 + (lc << 3));
        __builtin_nontemporal_store(p0, pr);
        __builtin_nontemporal_store(p1, pr + 1);
        short8 pk;
#pragma unroll
        for (int n = 0; n < 4; n++) { pk[n] = f2bs(p0[n]); pk[n + 4] = f2bs(p1[n]); }
        *(short8*)&Ps[(irow << 7) + ((lc ^ (irow & 15)) << 3)] = pk;
      }
    BAR_DRAIN16();  // staging done (vmcnt<=16: only the 16 P stores may remain), Ps visible
    // PV: Ps chunk c and Vs chunk c both hold j in [8c, 8c+8) -> k-maps agree
    __builtin_amdgcn_s_setprio(1);
#pragma unroll
    for (int kt4 = 0; kt4 < 4; kt4++) {
      short8 pa[2];
#pragma unroll
      for (int qm = 0; qm < 2; qm++) {
        int row = w * 32 + qm * 16 + lc;
        pa[qm] = *(const short8*)&Ps[(row << 7) + ((((kt4 << 2) + g) ^ (row & 15)) << 3)];
      }
#pragma unroll
      for (int dn = 0; dn < 4; dn++) {
        int d = dn * 16 + lc;
        short8 vb_ = *(const short8*)&Vs[(d << 7) + ((((kt4 << 2) + g) ^ (d & 15)) << 3)];
        acco[0][dn] = __builtin_amdgcn_mfma_f32_16x16x32_bf16(pa[0], vb_, acco[0][dn], 0, 0, 0);
        acco[1][dn] = __builtin_amdgcn_mfma_f32_16x16x32_bf16(pa[1], vb_, acco[1][dn], 0, 0, 0);
      }
    }
    __builtin_amdgcn_s_setprio(0);
    BAR_LGKM();  // LDS reads complete; Vs/Ps free for next iter (stores stay in flight)
    kb ^= 1;
  }
#pragma unroll
  for (int qm = 0; qm < 2; qm++)
#pragma unroll
    for (int dn = 0; dn < 4; dn++)
#pragma unroll
      for (int r = 0; r < 4; r++) {
        int srow = qb * 128 + w * 32 + qm * 16 + g * 4 + r;
        int col = h * 64 + dn * 16 + lc;
        ctx[(size_t)(b * 2048 + srow) * 1024 + col] = f2bs(acco[qm][dn][r]);
      }
#undef STAGE_K
#undef STAGE_V
}

// ---------------- K3: out projection + bias + residual -> x (fp32) ----------------
__global__ __launch_bounds__(256, 2) void oproj_kernel(
    const short* __restrict__ A, const short* __restrict__ W,
    const float* __restrict__ bo, const float* __restrict__ qres, float* __restrict__ xo) {
  __shared__ __align__(16) short As[128 * 64];
  __shared__ __align__(16) short Bs[128 * 64];
  const int t = threadIdx.x, w = t >> 6, lane = t & 63, g = lane >> 4, lc = lane & 15;
  const int wrow = (w >> 1) * 64, wcol = (w & 1) * 64;
  const int m0 = blockIdx.x * 128, n0 = blockIdx.y * 128;
  f32x4 acc[4][4] = {};
  for (int kt = 0; kt < 16; ++kt) {
    const int k0 = kt * 64;
    __syncthreads();
#pragma unroll
    for (int i = 0; i < 4; i++) {
      int cb = i * 256 + w * 64, ch = cb + lane, row = ch >> 3, c = ch & 7;
      async16(A + (size_t)(m0 + row) * 1024 + k0 + ((c ^ (row & 7)) << 3), (void*)&As[cb << 3]);
    }
#pragma unroll
    for (int i = 0; i < 4; i++) {
      int cb = i * 256 + w * 64, ch = cb + lane, row = ch >> 3, c = ch & 7;
      async16(W + (size_t)(n0 + row) * 1024 + k0 + ((c ^ (row & 7)) << 3), (void*)&Bs[cb << 3]);
    }
    __syncthreads();
#pragma unroll
    for (int kf = 0; kf < 2; ++kf) {
      short8 af[4], bf[4];
#pragma unroll
      for (int m = 0; m < 4; m++) {
        int row = wrow + m * 16 + lc;
        af[m] = *(const short8*)&As[(row << 6) + (((kf * 4 + g) ^ (row & 7)) << 3)];
      }
#pragma unroll
      for (int n = 0; n < 4; n++) {
        int row = wcol + n * 16 + lc;
        bf[n] = *(const short8*)&Bs[(row << 6) + (((kf * 4 + g) ^ (row & 7)) << 3)];
      }
#pragma unroll
      for (int m = 0; m < 4; m++)
#pragma unroll
        for (int n = 0; n < 4; n++)
          acc[m][n] = __builtin_amdgcn_mfma_f32_16x16x32_bf16(af[m], bf[n], acc[m][n], 0, 0, 0);
    }
  }
#pragma unroll
  for (int n = 0; n < 4; n++) {
    const int col = n0 + wcol + n * 16 + lc;
    const float bv_ = bo[col];
#pragma unroll
    for (int m = 0; m < 4; m++)
#pragma unroll
      for (int r = 0; r < 4; r++) {
        const int srow = m0 + wrow + m * 16 + g * 4 + r;
        size_t o = (size_t)srow * 1024 + col;
        xo[o] = acc[m][n][r] + bv_ + qres[o];
      }
  }
}

// ---------------- K4: LayerNorm over last dim (1024) ----------------
__global__ __launch_bounds__(256) void ln_kernel(const float* __restrict__ x,
                                                 const float* __restrict__ gamma,
                                                 const float* __restrict__ beta,
                                                 float* __restrict__ out) {
  const int row = blockIdx.x, t = threadIdx.x;
  const float4 v = ((const float4*)(x + (size_t)row * 1024))[t];
  float s = v.x + v.y + v.z + v.w;
  float sq = v.x * v.x + v.y * v.y + v.z * v.z + v.w * v.w;
#pragma unroll
  for (int off = 1; off < 64; off <<= 1) { s += __shfl_xor(s, off); sq += __shfl_xor(sq, off); }
  __shared__ float ss[4], sqs[4];
  const int w = t >> 6, lane = t & 63;
  if (lane == 0) { ss[w] = s; sqs[w] = sq; }
  __syncthreads();
  s = ss[0] + ss[1] + ss[2] + ss[3];
  sq = sqs[0] + sqs[1] + sqs[2] + sqs[3];
  const float mu = s * (1.f / 1024.f);
  const float var = sq * (1.f / 1024.f) - mu * mu;
  const float rs = rsqrtf(var + 1e-5f);
  const float4 gm = ((const float4*)gamma)[t];
  const float4 bt = ((const float4*)beta)[t];
  float4 o;
  o.x = (v.x - mu) * rs * gm.x + bt.x;
  o.y = (v.y - mu) * rs * gm.y + bt.y;
  o.z = (v.z - mu) * rs * gm.z + bt.z;
  o.w = (v.w - mu) * rs * gm.w + bt.w;
  ((float4*)(out + (size_t)row * 1024))[t] = o;
}

extern "C" void kernel_launch(void* const* d_in, const int* in_sizes, int n_in,
                              void* d_out, int out_size, void* d_ws, size_t ws_size,
                              hipStream_t stream) {
  (void)in_sizes; (void)n_in; (void)out_size; (void)ws_size;
  const float* q     = (const float*)d_in[0];
  const float* k     = (const float*)d_in[1];
  const float* v     = (const float*)d_in[2];
  const int*   mask  = (const int*)d_in[3];
  const float* Wq    = (const float*)d_in[4];
  const float* bq    = (const float*)d_in[5];
  const float* Wk    = (const float*)d_in[6];
  const float* bk    = (const float*)d_in[7];
  const float* Wv    = (const float*)d_in[8];
  const float* bv    = (const float*)d_in[9];
  const float* Wo    = (const float*)d_in[10];
  const float* bo    = (const float*)d_in[11];
  const float* gamma = (const float*)d_in[12];
  const float* beta  = (const float*)d_in[13];

  char* ws = (char*)d_ws;
  short* cvtdst = (short*)ws;                       // qb|kb|vb|Wq|Wk|Wv|Wo (bf16), 33.5MB
  short* Qh     = (short*)(ws + 33554432);
  short* Kh     = (short*)(ws + 41943040);
  short* Vt     = (short*)(ws + 50331648);
  unsigned* mbits  = (unsigned*)(ws + 58720256);
  unsigned* mflags = (unsigned*)(ws + 59768832);
  float* x   = (float*)ws;                          // overlays qb|kb (dead after proj)
  short* ctx = (short*)(ws + 16777216);             // overlays vb  (dead after proj)

  float* outln = (float*)d_out;
  float* Pout  = (float*)d_out + 4194304;

  hipMemsetAsync(mflags, 0, 2048, stream);
  cvt_mask_kernel<<<10240, 256, 0, stream>>>(q, k, v, Wq, Wk, Wv, Wo, cvtdst, mask, mbits, mflags);
  proj_kernel<<<dim3(32, 8, 3), 256, 0, stream>>>(cvtdst, cvtdst + 12582912, bq, bk, bv, Qh, Kh, Vt);
  attn_kernel<<<512, 256, 0, stream>>>(Qh, Kh, Vt, mbits, mflags, Pout, ctx);
  oproj_kernel<<<dim3(32, 8), 256, 0, stream>>>(ctx, cvtdst + 15728640, bo, q, x);
  ln_kernel<<<4096, 256, 0, stream>>>(x, gamma, beta, outln);
}

// Round 4
// 282.339 us; speedup vs baseline: 1.3433x; 1.3433x over previous
//
#include <hip/hip_runtime.h>
#include <hip/hip_bf16.h>

// B=2, S=2048, D=1024, H=16, HD=64.  All matmuls in bf16 MFMA (16x16x32).
// d_out = [ LN output (2*2048*1024 f32) | attention (2*16*2048*2048 f32) ]

typedef float f32x4 __attribute__((ext_vector_type(4)));
typedef short short8 __attribute__((ext_vector_type(8)));

#if __has_builtin(__builtin_amdgcn_exp2f)
#define EXP2(x) __builtin_amdgcn_exp2f(x)
#else
#define EXP2(x) exp2f(x)
#endif

#define QSCALE 0.18033688011112042f   /* log2(e)/8 : folds 1/sqrt(64) and exp->exp2 */
#define MASKNEG -1.4426950408889634e9f /* -1e9 * log2(e) -> exp2() == 0 */

__device__ __forceinline__ short f2bs(float f) {
  union { __hip_bfloat16 h; short s; } u;
  u.h = __float2bfloat16(f);
  return u.s;
}

__device__ __forceinline__ void async16(const void* g, void* l) {
  __builtin_amdgcn_global_load_lds(
      (const __attribute__((address_space(1))) unsigned int*)g,
      (__attribute__((address_space(3))) unsigned int*)l, 16, 0, 0);
}

// ---------------- K0: fp32 -> bf16 convert + mask bitmask (fused) ----------------
__global__ __launch_bounds__(256) void cvt_mask_kernel(
    const float* __restrict__ q, const float* __restrict__ k, const float* __restrict__ v,
    const float* __restrict__ wq, const float* __restrict__ wk, const float* __restrict__ wv,
    const float* __restrict__ wo, short* __restrict__ dst,
    const int* __restrict__ mask, unsigned* __restrict__ bits, unsigned* __restrict__ flags) {
  if (blockIdx.x < 8192) {
    long base = (long)blockIdx.x * 2048;  // block-uniform source select
    const float* src;
    if      (base <  4194304) src = q  + base;
    else if (base <  8388608) src = k  + (base - 4194304);
    else if (base < 12582912) src = v  + (base - 8388608);
    else if (base < 13631488) src = wq + (base - 12582912);
    else if (base < 14680064) src = wk + (base - 13631488);
    else if (base < 15728640) src = wv + (base - 14680064);
    else                      src = wo + (base - 15728640);
    int off = threadIdx.x * 8;
    float4 a = *(const float4*)(src + off);
    float4 b = *(const float4*)(src + off + 4);
    short8 o;
    o[0] = f2bs(a.x); o[1] = f2bs(a.y); o[2] = f2bs(a.z); o[3] = f2bs(a.w);
    o[4] = f2bs(b.x); o[5] = f2bs(b.y); o[6] = f2bs(b.z); o[7] = f2bs(b.w);
    *(short8*)(dst + base + off) = o;
  } else {
    int bid = blockIdx.x - 8192;
    int t = threadIdx.x, w = t >> 6, lane = t & 63;
    for (int it = 0; it < 16; ++it) {
      long gw = (long)it * 8192 + bid * 4 + w;
      long base = gw * 64;
      int mv = mask[base + lane];
      unsigned long long m = __ballot(mv != 0);
      if (lane == 0)  bits[gw * 2]     = (unsigned)m;
      if (lane == 32) bits[gw * 2 + 1] = (unsigned)(m >> 32);
      if (lane == 0 && m != 0xFFFFFFFFFFFFFFFFull) {
        long j = base & 2047, i = (base >> 11) & 2047, b = base >> 22;
        atomicOr(&flags[(int)(b * 256 + (i >> 7) * 16 + (j >> 7))], 1u);
      }
    }
  }
}

// ---------------- K1: QKV projection GEMM (128x128x64 tiles, 2-phase prefetch) ----------------
// mode 0: Qh[b][h][s][d] = (q@Wq^T + bq) * QSCALE
// mode 1: Kh[b][h][s][d] = (k@Wk^T + bk)
// mode 2: Vt[b][h][d][s] = (v@Wv^T + bv)   (plain transpose)
__global__ __launch_bounds__(256, 2) void proj_kernel(
    const short* __restrict__ Abase, const short* __restrict__ Wbase,
    const float* __restrict__ bq, const float* __restrict__ bk, const float* __restrict__ bv,
    short* __restrict__ Qh, short* __restrict__ Kh, short* __restrict__ Vt) {
  __shared__ __align__(16) short As[2][128 * 64];
  __shared__ __align__(16) short Bs[2][128 * 64];
  const int mode = blockIdx.z;
  const short* A = Abase + (size_t)mode * 4194304;
  const short* W = Wbase + (size_t)mode * 1048576;
  const float* bias = (mode == 0) ? bq : (mode == 1 ? bk : bv);
  const int t = threadIdx.x, w = t >> 6, lane = t & 63, g = lane >> 4, lc = lane & 15;
  const int wrow = (w >> 1) * 64, wcol = (w & 1) * 64;
  const int m0 = blockIdx.x * 128, n0 = blockIdx.y * 128;

#define PSTAGE(buf, k0)                                                                     \
  do {                                                                                      \
    _Pragma("unroll") for (int i_ = 0; i_ < 4; i_++) {                                      \
      int cb = i_ * 256 + w * 64, ch = cb + lane, row = ch >> 3, c = ch & 7;                \
      int so = ((c ^ (row & 7)) << 3);                                                      \
      async16(A + (size_t)(m0 + row) * 1024 + (k0) + so, (void*)&As[buf][cb << 3]);         \
      async16(W + (size_t)(n0 + row) * 1024 + (k0) + so, (void*)&Bs[buf][cb << 3]);         \
    }                                                                                       \
  } while (0)

  f32x4 acc[4][4] = {};
  PSTAGE(0, 0);
  __syncthreads();
  int pb = 0;
  for (int kt = 0; kt < 16; ++kt) {
    if (kt < 15) PSTAGE(pb ^ 1, (kt + 1) * 64);  // prefetch next tile (hidden under compute)
#pragma unroll
    for (int kf = 0; kf < 2; ++kf) {
      short8 af[4], bf[4];
#pragma unroll
      for (int m = 0; m < 4; m++) {
        int row = wrow + m * 16 + lc;
        af[m] = *(const short8*)&As[pb][(row << 6) + (((kf * 4 + g) ^ (row & 7)) << 3)];
      }
#pragma unroll
      for (int n = 0; n < 4; n++) {
        int row = wcol + n * 16 + lc;
        bf[n] = *(const short8*)&Bs[pb][(row << 6) + (((kf * 4 + g) ^ (row & 7)) << 3)];
      }
      __builtin_amdgcn_s_setprio(1);
#pragma unroll
      for (int m = 0; m < 4; m++)
#pragma unroll
        for (int n = 0; n < 4; n++)
          acc[m][n] = __builtin_amdgcn_mfma_f32_16x16x32_bf16(af[m], bf[n], acc[m][n], 0, 0, 0);
      __builtin_amdgcn_s_setprio(0);
    }
    __syncthreads();  // prefetch drained + all reads of As[pb] done
    pb ^= 1;
  }
#undef PSTAGE
#pragma unroll
  for (int n = 0; n < 4; n++) {
    const int col = n0 + wcol + n * 16 + lc;
    const float bv_ = bias[col];
    const int h = col >> 6, d = col & 63;
#pragma unroll
    for (int m = 0; m < 4; m++)
#pragma unroll
      for (int r = 0; r < 4; r++) {
        const int srow = m0 + wrow + m * 16 + g * 4 + r;
        const int b = srow >> 11, s = srow & 2047;
        float val = acc[m][n][r] + bv_;
        if (mode == 0)
          Qh[((size_t)(b * 16 + h) * 2048 + s) * 64 + d] = f2bs(val * QSCALE);
        else if (mode == 1)
          Kh[((size_t)(b * 16 + h) * 2048 + s) * 64 + d] = f2bs(val);
        else
          Vt[((size_t)(b * 16 + h) * 64 + d) * 2048 + s] = f2bs(val);
      }
  }
}

// ---------------- K2: fused attention (round-2 structure + setprio) ----------------
// Pass A (swapped QK^T): row sums l only (no max; scores are O(1), exp2-safe).
// Pass B: recompute S with j permuted so each lane owns 8 consecutive j ->
//         dwordx4 P stores, b128 Ps writes, plain V^T chunks.
// Ks swizzle s(row) = (row&7)^((row>>3)&7) serves both read patterns.
__global__ __launch_bounds__(256, 2) void attn_kernel(
    const short* __restrict__ Qh, const short* __restrict__ Kh, const short* __restrict__ Vt,
    const unsigned* __restrict__ mbits, const unsigned* __restrict__ mflags,
    float* __restrict__ Pout, short* __restrict__ ctx) {
  __shared__ __align__(16) short Ks[2][128 * 64];  // double-buffered K tile
  __shared__ __align__(16) short Vs[64 * 128];     // V^T tile [d][j], chunk c = j in [8c,8c+8)
  __shared__ __align__(16) short Ps[128 * 128];    // P tile  [i][j], chunk c = j in [8c,8c+8)
  // XCD swizzle: xcd gets 4 bh, 16 qb each -> K/V working set 2MB per XCD L2
  const int L = blockIdx.x;
  const int xcd = L & 7, idx = L >> 3;
  const int bh = xcd + ((idx >> 4) << 3);
  const int qb = idx & 15;
  const int b = bh >> 4, h = bh & 15;
  const int t = threadIdx.x, w = t >> 6, lane = t & 63, g = lane >> 4, lc = lane & 15;
  const short* Qp = Qh + (size_t)bh * 2048 * 64;
  const short* Kp = Kh + (size_t)bh * 2048 * 64;
  const short* Vp = Vt + (size_t)bh * 64 * 2048;
  float* Pb = Pout + ((size_t)bh * 2048 + qb * 128) * 2048;

  short8 qf[2][2];
#pragma unroll
  for (int qm = 0; qm < 2; qm++)
#pragma unroll
    for (int kf = 0; kf < 2; kf++)
      qf[qm][kf] = *(const short8*)(Qp + (size_t)(qb * 128 + w * 32 + qm * 16 + lc) * 64 + kf * 32 + g * 8);

#define STAGE_K(buf, j0)                                                                   \
  do {                                                                                     \
    _Pragma("unroll") for (int i_ = 0; i_ < 4; i_++) {                                     \
      int cb = i_ * 256 + w * 64, ch = cb + lane, row = ch >> 3, c = ch & 7;               \
      int sc = c ^ (row & 7) ^ ((row >> 3) & 7);                                           \
      async16(Kp + (size_t)((j0) + row) * 64 + (sc << 3), (void*)&Ks[buf][cb << 3]);       \
    }                                                                                      \
  } while (0)
#define STAGE_V(j0)                                                                        \
  do {                                                                                     \
    _Pragma("unroll") for (int i_ = 0; i_ < 4; i_++) {                                     \
      int cb = i_ * 256 + w * 64, ch = cb + lane, row = ch >> 4, c = ch & 15;              \
      async16(Vp + (size_t)row * 2048 + (j0) + ((c ^ (row & 15)) << 3), (void*)&Vs[cb << 3]); \
    }                                                                                      \
  } while (0)

  // ---- pass A: l only, swapped operands ----
  float lsum[2] = {0.f, 0.f};
  int kb = 0;
  STAGE_K(0, 0);
  __syncthreads();
  for (int it = 0; it < 16; ++it) {
    if (it < 15) STAGE_K(kb ^ 1, (it + 1) * 128);
    f32x4 acc[2][8] = {};
    __builtin_amdgcn_s_setprio(1);
#pragma unroll
    for (int kf = 0; kf < 2; kf++)
#pragma unroll
      for (int n = 0; n < 8; n++) {
        int row = n * 16 + lc;
        int sc = (kf * 4 + g) ^ (row & 7) ^ ((row >> 3) & 7);
        short8 kfr = *(const short8*)&Ks[kb][(row << 6) + (sc << 3)];
        acc[0][n] = __builtin_amdgcn_mfma_f32_16x16x32_bf16(kfr, qf[0][kf], acc[0][n], 0, 0, 0);
        acc[1][n] = __builtin_amdgcn_mfma_f32_16x16x32_bf16(kfr, qf[1][kf], acc[1][n], 0, 0, 0);
      }
    __builtin_amdgcn_s_setprio(0);
    unsigned flg = mflags[b * 256 + qb * 16 + it];
    if (flg) {
#pragma unroll
      for (int qm = 0; qm < 2; qm++) {
        int ig = qb * 128 + w * 32 + qm * 16 + lc;
        uint4 mw = *(const uint4*)(mbits + ((size_t)b * 2048 + ig) * 64 + it * 4);
#pragma unroll
        for (int n = 0; n < 8; n++) {
          unsigned bw = (n >> 1) == 0 ? mw.x : ((n >> 1) == 1 ? mw.y : ((n >> 1) == 2 ? mw.z : mw.w));
#pragma unroll
          for (int r = 0; r < 4; r++)
            if (!((bw >> (((n & 1) << 4) + g * 4 + r)) & 1u)) acc[qm][n][r] = MASKNEG;
        }
      }
    }
#pragma unroll
    for (int qm = 0; qm < 2; qm++) {
      float s_ = 0.f;
#pragma unroll
      for (int n = 0; n < 8; n++)
#pragma unroll
        for (int r = 0; r < 4; r++) s_ += EXP2(acc[qm][n][r]);
      s_ += __shfl_xor(s_, 16);
      s_ += __shfl_xor(s_, 32);
      lsum[qm] += s_;
    }
    __syncthreads();  // drains prefetch; Ks[kb] free for overwrite next iter
    kb ^= 1;
  }
  // exchange l across lanes via LDS (Vs unused so far)
  float* ls = (float*)Vs;
  if (g == 0) { ls[w * 32 + lc] = lsum[0]; ls[w * 32 + 16 + lc] = lsum[1]; }
  __syncthreads();
  float linv[8];
#pragma unroll
  for (int qm = 0; qm < 2; qm++)
#pragma unroll
    for (int r = 0; r < 4; r++) linv[qm * 4 + r] = 1.0f / ls[w * 32 + qm * 16 + g * 4 + r];
  kb = 0;
  STAGE_K(0, 0);
  __syncthreads();  // all lanes read ls before Vs overwritten; Ks[0] ready

  // ---- pass B ----
  f32x4 acco[2][4] = {};
  for (int it = 0; it < 16; ++it) {
    const int j0 = it * 128;
    STAGE_V(j0);
    if (it < 15) STAGE_K(kb ^ 1, j0 + 128);
    f32x4 accs[2][8] = {};
    __builtin_amdgcn_s_setprio(1);
#pragma unroll
    for (int kf = 0; kf < 2; kf++)
#pragma unroll
      for (int n = 0; n < 8; n++) {
        int row = lc * 8 + n;  // permuted j: lane lc owns j in [8lc, 8lc+8)
        int sc = (kf * 4 + g) ^ n ^ (lc & 7);
        short8 kfr = *(const short8*)&Ks[kb][(row << 6) + (sc << 3)];
        accs[0][n] = __builtin_amdgcn_mfma_f32_16x16x32_bf16(qf[0][kf], kfr, accs[0][n], 0, 0, 0);
        accs[1][n] = __builtin_amdgcn_mfma_f32_16x16x32_bf16(qf[1][kf], kfr, accs[1][n], 0, 0, 0);
      }
    __builtin_amdgcn_s_setprio(0);
    unsigned flg = mflags[b * 256 + qb * 16 + it];
    if (flg) {
#pragma unroll
      for (int qm = 0; qm < 2; qm++)
#pragma unroll
        for (int r = 0; r < 4; r++) {
          int ig = qb * 128 + w * 32 + qm * 16 + g * 4 + r;
          uint4 mw = *(const uint4*)(mbits + ((size_t)b * 2048 + ig) * 64 + it * 4);
          unsigned w01 = (lc & 4) ? mw.y : mw.x;
          unsigned w23 = (lc & 4) ? mw.w : mw.z;
          unsigned wsel = (lc & 8) ? w23 : w01;
#pragma unroll
          for (int n = 0; n < 8; n++)
            if (!((wsel >> (((lc & 3) << 3) + n)) & 1u)) accs[qm][n][r] = MASKNEG;
        }
    }
    // P = exp2(s) / l : two dwordx4 global stores + one b128 LDS write per (qm,r)
#pragma unroll
    for (int qm = 0; qm < 2; qm++)
#pragma unroll
      for (int r = 0; r < 4; r++) {
        const float li = linv[qm * 4 + r];
        const int irow = w * 32 + qm * 16 + g * 4 + r;
        f32x4 p0, p1;
#pragma unroll
        for (int n = 0; n < 4; n++) p0[n] = EXP2(accs[qm][n][r]) * li;
#pragma unroll
        for (int n = 0; n < 4; n++) p1[n] = EXP2(accs[qm][n + 4][r]) * li;
        float* pr = Pb + (size_t)irow * 2048 + j0 + (lc << 3);
        *(f32x4*)pr = p0;
        *(f32x4*)(pr + 4) = p1;
        short8 pk;
#pragma unroll
        for (int n = 0; n < 4; n++) { pk[n] = f2bs(p0[n]); pk[n + 4] = f2bs(p1[n]); }
        *(short8*)&Ps[(irow << 7) + ((lc ^ (irow & 15)) << 3)] = pk;
      }
    __syncthreads();  // Ps visible, Vs staged, Ks[kb^1] staged
    // PV: Ps chunk c and Vs chunk c both hold j in [8c, 8c+8) -> k-maps agree
    __builtin_amdgcn_s_setprio(1);
#pragma unroll
    for (int kt4 = 0; kt4 < 4; kt4++) {
      short8 pa[2];
#pragma unroll
      for (int qm = 0; qm < 2; qm++) {
        int row = w * 32 + qm * 16 + lc;
        pa[qm] = *(const short8*)&Ps[(row << 7) + ((((kt4 << 2) + g) ^ (row & 15)) << 3)];
      }
#pragma unroll
      for (int dn = 0; dn < 4; dn++) {
        int d = dn * 16 + lc;
        short8 vb_ = *(const short8*)&Vs[(d << 7) + ((((kt4 << 2) + g) ^ (d & 15)) << 3)];
        acco[0][dn] = __builtin_amdgcn_mfma_f32_16x16x32_bf16(pa[0], vb_, acco[0][dn], 0, 0, 0);
        acco[1][dn] = __builtin_amdgcn_mfma_f32_16x16x32_bf16(pa[1], vb_, acco[1][dn], 0, 0, 0);
      }
    }
    __builtin_amdgcn_s_setprio(0);
    __syncthreads();  // Vs/Ps free for next iter
    kb ^= 1;
  }
#pragma unroll
  for (int qm = 0; qm < 2; qm++)
#pragma unroll
    for (int dn = 0; dn < 4; dn++)
#pragma unroll
      for (int r = 0; r < 4; r++) {
        int srow = qb * 128 + w * 32 + qm * 16 + g * 4 + r;
        int col = h * 64 + dn * 16 + lc;
        ctx[(size_t)(b * 2048 + srow) * 1024 + col] = f2bs(acco[qm][dn][r]);
      }
#undef STAGE_K
#undef STAGE_V
}

// ---------------- K3: out projection + bias + residual -> x (fp32), 2-phase prefetch ----------------
__global__ __launch_bounds__(256, 2) void oproj_kernel(
    const short* __restrict__ A, const short* __restrict__ W,
    const float* __restrict__ bo, const float* __restrict__ qres, float* __restrict__ xo) {
  __shared__ __align__(16) short As[2][128 * 64];
  __shared__ __align__(16) short Bs[2][128 * 64];
  const int t = threadIdx.x, w = t >> 6, lane = t & 63, g = lane >> 4, lc = lane & 15;
  const int wrow = (w >> 1) * 64, wcol = (w & 1) * 64;
  const int m0 = blockIdx.x * 128, n0 = blockIdx.y * 128;

#define OSTAGE(buf, k0)                                                                     \
  do {                                                                                      \
    _Pragma("unroll") for (int i_ = 0; i_ < 4; i_++) {                                      \
      int cb = i_ * 256 + w * 64, ch = cb + lane, row = ch >> 3, c = ch & 7;                \
      int so = ((c ^ (row & 7)) << 3);                                                      \
      async16(A + (size_t)(m0 + row) * 1024 + (k0) + so, (void*)&As[buf][cb << 3]);         \
      async16(W + (size_t)(n0 + row) * 1024 + (k0) + so, (void*)&Bs[buf][cb << 3]);         \
    }                                                                                       \
  } while (0)

  f32x4 acc[4][4] = {};
  OSTAGE(0, 0);
  __syncthreads();
  int pb = 0;
  for (int kt = 0; kt < 16; ++kt) {
    if (kt < 15) OSTAGE(pb ^ 1, (kt + 1) * 64);
#pragma unroll
    for (int kf = 0; kf < 2; ++kf) {
      short8 af[4], bf[4];
#pragma unroll
      for (int m = 0; m < 4; m++) {
        int row = wrow + m * 16 + lc;
        af[m] = *(const short8*)&As[pb][(row << 6) + (((kf * 4 + g) ^ (row & 7)) << 3)];
      }
#pragma unroll
      for (int n = 0; n < 4; n++) {
        int row = wcol + n * 16 + lc;
        bf[n] = *(const short8*)&Bs[pb][(row << 6) + (((kf * 4 + g) ^ (row & 7)) << 3)];
      }
      __builtin_amdgcn_s_setprio(1);
#pragma unroll
      for (int m = 0; m < 4; m++)
#pragma unroll
        for (int n = 0; n < 4; n++)
          acc[m][n] = __builtin_amdgcn_mfma_f32_16x16x32_bf16(af[m], bf[n], acc[m][n], 0, 0, 0);
      __builtin_amdgcn_s_setprio(0);
    }
    __syncthreads();
    pb ^= 1;
  }
#undef OSTAGE
#pragma unroll
  for (int n = 0; n < 4; n++) {
    const int col = n0 + wcol + n * 16 + lc;
    const float bv_ = bo[col];
#pragma unroll
    for (int m = 0; m < 4; m++)
#pragma unroll
      for (int r = 0; r < 4; r++) {
        const int srow = m0 + wrow + m * 16 + g * 4 + r;
        size_t o = (size_t)srow * 1024 + col;
        xo[o] = acc[m][n][r] + bv_ + qres[o];
      }
  }
}

// ---------------- K4: LayerNorm over last dim (1024) ----------------
__global__ __launch_bounds__(256) void ln_kernel(const float* __restrict__ x,
                                                 const float* __restrict__ gamma,
                                                 const float* __restrict__ beta,
                                                 float* __restrict__ out) {
  const int row = blockIdx.x, t = threadIdx.x;
  const float4 v = ((const float4*)(x + (size_t)row * 1024))[t];
  float s = v.x + v.y + v.z + v.w;
  float sq = v.x * v.x + v.y * v.y + v.z * v.z + v.w * v.w;
#pragma unroll
  for (int off = 1; off < 64; off <<= 1) { s += __shfl_xor(s, off); sq += __shfl_xor(sq, off); }
  __shared__ float ss[4], sqs[4];
  const int w = t >> 6, lane = t & 63;
  if (lane == 0) { ss[w] = s; sqs[w] = sq; }
  __syncthreads();
  s = ss[0] + ss[1] + ss[2] + ss[3];
  sq = sqs[0] + sqs[1] + sqs[2] + sqs[3];
  const float mu = s * (1.f / 1024.f);
  const float var = sq * (1.f / 1024.f) - mu * mu;
  const float rs = rsqrtf(var + 1e-5f);
  const float4 gm = ((const float4*)gamma)[t];
  const float4 bt = ((const float4*)beta)[t];
  float4 o;
  o.x = (v.x - mu) * rs * gm.x + bt.x;
  o.y = (v.y - mu) * rs * gm.y + bt.y;
  o.z = (v.z - mu) * rs * gm.z + bt.z;
  o.w = (v.w - mu) * rs * gm.w + bt.w;
  ((float4*)(out + (size_t)row * 1024))[t] = o;
}

extern "C" void kernel_launch(void* const* d_in, const int* in_sizes, int n_in,
                              void* d_out, int out_size, void* d_ws, size_t ws_size,
                              hipStream_t stream) {
  (void)in_sizes; (void)n_in; (void)out_size; (void)ws_size;
  const float* q     = (const float*)d_in[0];
  const float* k     = (const float*)d_in[1];
  const float* v     = (const float*)d_in[2];
  const int*   mask  = (const int*)d_in[3];
  const float* Wq    = (const float*)d_in[4];
  const float* bq    = (const float*)d_in[5];
  const float* Wk    = (const float*)d_in[6];
  const float* bk    = (const float*)d_in[7];
  const float* Wv    = (const float*)d_in[8];
  const float* bv    = (const float*)d_in[9];
  const float* Wo    = (const float*)d_in[10];
  const float* bo    = (const float*)d_in[11];
  const float* gamma = (const float*)d_in[12];
  const float* beta  = (const float*)d_in[13];

  char* ws = (char*)d_ws;
  short* cvtdst = (short*)ws;                       // qb|kb|vb|Wq|Wk|Wv|Wo (bf16), 33.5MB
  short* Qh     = (short*)(ws + 33554432);
  short* Kh     = (short*)(ws + 41943040);
  short* Vt     = (short*)(ws + 50331648);
  unsigned* mbits  = (unsigned*)(ws + 58720256);
  unsigned* mflags = (unsigned*)(ws + 59768832);
  float* x   = (float*)ws;                          // overlays qb|kb (dead after proj)
  short* ctx = (short*)(ws + 16777216);             // overlays vb  (dead after proj)

  float* outln = (float*)d_out;
  float* Pout  = (float*)d_out + 4194304;

  hipMemsetAsync(mflags, 0, 2048, stream);
  cvt_mask_kernel<<<10240, 256, 0, stream>>>(q, k, v, Wq, Wk, Wv, Wo, cvtdst, mask, mbits, mflags);
  proj_kernel<<<dim3(32, 8, 3), 256, 0, stream>>>(cvtdst, cvtdst + 12582912, bq, bk, bv, Qh, Kh, Vt);
  attn_kernel<<<512, 256, 0, stream>>>(Qh, Kh, Vt, mbits, mflags, Pout, ctx);
  oproj_kernel<<<dim3(32, 8), 256, 0, stream>>>(ctx, cvtdst + 15728640, bo, q, x);
  ln_kernel<<<4096, 256, 0, stream>>>(x, gamma, beta, outln);
}